// Round 7
// baseline (544.997 us; speedup 1.0000x reference)
//
#include <hip/hip_runtime.h>
#include <hip/hip_bf16.h>
#include <cstdint>
#include <cstddef>

typedef __hip_bfloat16 bf16;
typedef __attribute__((ext_vector_type(8))) short short8;
typedef __attribute__((ext_vector_type(4))) float f32x4;

// ---- problem constants ----
#define B_   2
#define L_   4096
#define DM_  768      // d_model
#define DI_  1536     // d_inner
#define NH_  24       // nheads
#define HD_  64       // headdim
#define DS_  64       // d_state
#define CH_  256      // chunk
#define NC_  16       // n chunks
#define CD_  1664     // conv dim
#define DIP_ 3248     // d_in_proj
#define NPAD_ 3328    // in_proj N padded to 26*128
#define EPS_ 1e-5f

#define ROWS_ (B_*L_)        // 8192
#define BB4_  (2*B_)         // 4 ssd batches

#define LDT  72              // Gt LDS row stride (shorts)

__device__ __forceinline__ float b2f(bf16 v) { return __bfloat162float(v); }
__device__ __forceinline__ bf16  f2b(float v) { return __float2bfloat16(v); }
__device__ __forceinline__ float sb2f(short s) {
    bf16 t; __builtin_memcpy(&t, &s, 2); return __bfloat162float(t);
}
__device__ __forceinline__ short f2s(float v) {
    bf16 t = __float2bfloat16(v); short s; __builtin_memcpy(&s, &t, 2); return s;
}
__device__ __forceinline__ void gl_lds16(const void* g, void* l) {
    __builtin_amdgcn_global_load_lds((const __attribute__((address_space(1))) unsigned int*)g,
                                     (__attribute__((address_space(3))) unsigned int*)l,
                                     16, 0, 0);
}

// ------------------------------------------------------------------
// cast f32 -> bf16 (out_proj weights)
// ------------------------------------------------------------------
__global__ __launch_bounds__(256) void cast_f2b(const float* __restrict__ s,
                                                bf16* __restrict__ d, int n) {
    int i = (blockIdx.x * 256 + threadIdx.x) * 4;
    if (i + 3 < n) {
        float4 v = *(const float4*)(s + i);
        d[i]   = f2b(v.x); d[i+1] = f2b(v.y);
        d[i+2] = f2b(v.z); d[i+3] = f2b(v.w);
    } else {
        for (int k = i; k < n; k++) d[k] = f2b(s[k]);
    }
}

// cast + zero-pad rows [3248,3328) for in_proj weights
__global__ __launch_bounds__(256) void cast_pad_inproj(const float* __restrict__ s,
                                                       bf16* __restrict__ d) {
    int i = (blockIdx.x * 256 + threadIdx.x) * 4;
    const int nsrc = DIP_ * DM_;
    const int ntot = NPAD_ * DM_;
    if (i >= ntot) return;
    if (i + 3 < nsrc) {
        float4 v = *(const float4*)(s + i);
        d[i]   = f2b(v.x); d[i+1] = f2b(v.y);
        d[i+2] = f2b(v.z); d[i+3] = f2b(v.w);
    } else {
        for (int k = i; k < i + 4 && k < ntot; k++)
            d[k] = (k < nsrc) ? f2b(s[k]) : f2b(0.f);
    }
}

// ------------------------------------------------------------------
// LayerNorm: one block per row (768), bf16 out
// ------------------------------------------------------------------
__global__ __launch_bounds__(256) void ln_kernel(const float* __restrict__ x,
                                                 const float* __restrict__ w,
                                                 const float* __restrict__ bb,
                                                 bf16* __restrict__ u) {
    int row = blockIdx.x, tid = threadIdx.x;
    const float* xr = x + (size_t)row * DM_;
    float v0 = xr[tid], v1 = xr[tid + 256], v2 = xr[tid + 512];
    float s = v0 + v1 + v2;
    float q = v0*v0 + v1*v1 + v2*v2;
    for (int off = 32; off > 0; off >>= 1) {
        s += __shfl_down(s, off);
        q += __shfl_down(q, off);
    }
    __shared__ float rs[4], rq[4];
    __shared__ float mean_s, rstd_s;
    int lane = tid & 63, wid = tid >> 6;
    if (!lane) { rs[wid] = s; rq[wid] = q; }
    __syncthreads();
    if (!tid) {
        float S = rs[0]+rs[1]+rs[2]+rs[3];
        float Q = rq[0]+rq[1]+rq[2]+rq[3];
        float mu = S / (float)DM_;
        float var = Q / (float)DM_ - mu*mu;
        mean_s = mu; rstd_s = rsqrtf(var + EPS_);
    }
    __syncthreads();
    float mu = mean_s, rstd = rstd_s;
    bf16* ur = u + (size_t)row * DM_;
    ur[tid]       = f2b((v0 - mu) * rstd * w[tid]       + bb[tid]);
    ur[tid + 256] = f2b((v1 - mu) * rstd * w[tid + 256] + bb[tid + 256]);
    ur[tid + 512] = f2b((v2 - mu) * rstd * w[tid + 512] + bb[tid + 512]);
}

// ------------------------------------------------------------------
// m97-style GEMM with global_load_lds + XOR swizzle.
// Tile 128x128, BK=32, 4 waves (2x2), each wave 64x64.
// LDS linear [128][32] shorts; staging source pre-swizzled:
//   lane l loads col-slot ((l&3)^((l>>3)&3)); read slot = g^((fr>>1)&3).
// ------------------------------------------------------------------
__global__ __launch_bounds__(256) void gemm_gl_inproj(const bf16* __restrict__ A,
                                                      const bf16* __restrict__ W,
                                                      bf16* __restrict__ zbuf,
                                                      bf16* __restrict__ xbc,
                                                      float* __restrict__ dtr) {
    __shared__ short As[128 * 32];
    __shared__ short Ws[128 * 32];
    int tid = threadIdx.x;
    int wave = tid >> 6, lane = tid & 63;
    int wm = (wave >> 1) * 64, wn = (wave & 1) * 64;
    int bm = blockIdx.y * 128, bn = blockIdx.x * 128;
    int fr = lane & 15, g = lane >> 4;
    const int K = DM_;
    int srow = lane >> 2;
    int scol = ((lane & 3) ^ ((lane >> 3) & 3)) * 8;
    int rsl = (g ^ ((fr >> 1) & 3)) * 8;
    const short* Ag = (const short*)A;
    const short* Wg = (const short*)W;
    f32x4 acc[4][4] = {};
    for (int k0 = 0; k0 < K; k0 += 32) {
        __syncthreads();
        #pragma unroll
        for (int q = 0; q < 2; q++) {
            gl_lds16(Ag + (size_t)(bm + q*64 + wave*16 + srow) * K + k0 + scol,
                     &As[(q*64 + wave*16) * 32]);
            gl_lds16(Wg + (size_t)(bn + q*64 + wave*16 + srow) * K + k0 + scol,
                     &Ws[(q*64 + wave*16) * 32]);
        }
        __syncthreads();
        short8 af[4], wf[4];
        #pragma unroll
        for (int i = 0; i < 4; i++)
            af[i] = *(const short8*)&As[(wm + i*16 + fr)*32 + rsl];
        #pragma unroll
        for (int j = 0; j < 4; j++)
            wf[j] = *(const short8*)&Ws[(wn + j*16 + fr)*32 + rsl];
        #pragma unroll
        for (int i = 0; i < 4; i++)
            #pragma unroll
            for (int j = 0; j < 4; j++)
                acc[i][j] = __builtin_amdgcn_mfma_f32_16x16x32_bf16(af[i], wf[j], acc[i][j], 0, 0, 0);
    }
    int rg = (lane >> 4) * 4;
    #pragma unroll
    for (int i = 0; i < 4; i++) {
        int mrow = bm + wm + i*16 + rg;
        #pragma unroll
        for (int j = 0; j < 4; j++) {
            int ncol = bn + wn + j*16 + fr;
            #pragma unroll
            for (int r = 0; r < 4; r++) {
                float v = acc[i][j][r];
                int m = mrow + r;
                if (ncol < DI_)            zbuf[(size_t)m * DI_ + ncol] = f2b(v);
                else if (ncol < DI_ + CD_) xbc[(size_t)m * CD_ + (ncol - DI_)] = f2b(v);
                else if (ncol < DIP_)      dtr[(size_t)m * 48 + (ncol - DI_ - CD_)] = v;
            }
        }
    }
}

__global__ __launch_bounds__(256) void gemm_gl_out(const bf16* __restrict__ A,
                                                   const bf16* __restrict__ W,
                                                   const float* __restrict__ resid,
                                                   float* __restrict__ C) {
    __shared__ short As[128 * 32];
    __shared__ short Ws[128 * 32];
    int tid = threadIdx.x;
    int wave = tid >> 6, lane = tid & 63;
    int wm = (wave >> 1) * 64, wn = (wave & 1) * 64;
    int bm = blockIdx.y * 128, bn = blockIdx.x * 128;
    int fr = lane & 15, g = lane >> 4;
    const int K = DI_;
    int srow = lane >> 2;
    int scol = ((lane & 3) ^ ((lane >> 3) & 3)) * 8;
    int rsl = (g ^ ((fr >> 1) & 3)) * 8;
    const short* Ag = (const short*)A;
    const short* Wg = (const short*)W;
    f32x4 acc[4][4] = {};
    for (int k0 = 0; k0 < K; k0 += 32) {
        __syncthreads();
        #pragma unroll
        for (int q = 0; q < 2; q++) {
            gl_lds16(Ag + (size_t)(bm + q*64 + wave*16 + srow) * K + k0 + scol,
                     &As[(q*64 + wave*16) * 32]);
            gl_lds16(Wg + (size_t)(bn + q*64 + wave*16 + srow) * K + k0 + scol,
                     &Ws[(q*64 + wave*16) * 32]);
        }
        __syncthreads();
        short8 af[4], wf[4];
        #pragma unroll
        for (int i = 0; i < 4; i++)
            af[i] = *(const short8*)&As[(wm + i*16 + fr)*32 + rsl];
        #pragma unroll
        for (int j = 0; j < 4; j++)
            wf[j] = *(const short8*)&Ws[(wn + j*16 + fr)*32 + rsl];
        #pragma unroll
        for (int i = 0; i < 4; i++)
            #pragma unroll
            for (int j = 0; j < 4; j++)
                acc[i][j] = __builtin_amdgcn_mfma_f32_16x16x32_bf16(af[i], wf[j], acc[i][j], 0, 0, 0);
    }
    int rg = (lane >> 4) * 4;
    #pragma unroll
    for (int i = 0; i < 4; i++) {
        int mrow = bm + wm + i*16 + rg;
        #pragma unroll
        for (int j = 0; j < 4; j++) {
            int ncol = bn + wn + j*16 + fr;
            #pragma unroll
            for (int r = 0; r < 4; r++) {
                int m = mrow + r;
                C[(size_t)m * DM_ + ncol] = acc[i][j][r] + resid[(size_t)m * DM_ + ncol];
            }
        }
    }
}

// ------------------------------------------------------------------
// Depthwise causal conv7 + SiLU, vectorized: 8 channels x 4 t per thread
// ------------------------------------------------------------------
__global__ __launch_bounds__(256) void conv_kernel(const bf16* __restrict__ xbc,
                                                   const float* __restrict__ cw,
                                                   const float* __restrict__ cb,
                                                   bf16* __restrict__ out) {
    int g = blockIdx.x * 256 + threadIdx.x;
    int cg = g % 208;
    int tq = g / 208;
    int b = tq >> 10;
    int t0 = (tq & 1023) * 4;
    int c8 = cg * 8;
    const short* src = (const short*)xbc + (size_t)(b * L_) * CD_ + c8;

    float w[7][8], acc[4][8];
    #pragma unroll
    for (int k = 0; k < 8; k++) {
        #pragma unroll
        for (int j = 0; j < 7; j++) w[j][k] = cw[(c8 + k) * 7 + j];
        float bias = cb[c8 + k];
        #pragma unroll
        for (int q = 0; q < 4; q++) acc[q][k] = bias;
    }
    #pragma unroll
    for (int m = 0; m < 10; m++) {
        int tt = t0 - 6 + m;
        float row[8];
        if (tt >= 0) {
            short8 v = *(const short8*)(src + (size_t)tt * CD_);
            #pragma unroll
            for (int k = 0; k < 8; k++) row[k] = sb2f(v[k]);
        } else {
            #pragma unroll
            for (int k = 0; k < 8; k++) row[k] = 0.f;
        }
        #pragma unroll
        for (int q = 0; q < 4; q++) {
            int j = m - q;
            if (j >= 0 && j < 7) {
                #pragma unroll
                for (int k = 0; k < 8; k++) acc[q][k] += row[k] * w[j][k];
            }
        }
    }
    #pragma unroll
    for (int q = 0; q < 4; q++) {
        short8 o;
        #pragma unroll
        for (int k = 0; k < 8; k++) {
            float a = acc[q][k];
            a = a / (1.f + __expf(-a));
            o[k] = f2s(a);
        }
        *(short8*)((short*)out + (size_t)(b * L_ + t0 + q) * CD_ + c8) = o;
    }
}

// ------------------------------------------------------------------
// dt: softplus(dt2 + bias) with flip for bwd batches
// ------------------------------------------------------------------
__global__ __launch_bounds__(256) void dt_kernel(const float* __restrict__ dtr,
                                                 const float* __restrict__ dt_bias,
                                                 float* __restrict__ dt4) {
    int idx = blockIdx.x * 256 + threadIdx.x;
    if (idx >= BB4_ * L_ * NH_) return;
    int h = idx % NH_;
    int t = (idx / NH_) % L_;
    int bbx = idx / (NH_ * L_);
    int bp = bbx & 1;
    float raw;
    if (bbx < 2) raw = dtr[((size_t)(bp * L_ + t)) * 48 + h];
    else         raw = dtr[((size_t)(bp * L_ + (L_ - 1 - t))) * 48 + NH_ + h];
    float v = raw + dt_bias[h];
    float dt = (v > 20.f) ? v : log1pf(__expf(v));
    dt4[idx] = dt;
}

// ------------------------------------------------------------------
// per-chunk inclusive cumsum of dt*A
// ------------------------------------------------------------------
__global__ __launch_bounds__(256) void scan_kernel(const float* __restrict__ dt4,
                                                   const float* __restrict__ A_log,
                                                   float* __restrict__ Acum) {
    int bid = blockIdx.x;
    int c  = bid % NC_;
    int h  = (bid / NC_) % NH_;
    int bbx = bid / (NC_ * NH_);
    int l = threadIdx.x;
    float Ah = -__expf(A_log[h]);
    float val = dt4[((size_t)(bbx * L_) + c * CH_ + l) * NH_ + h] * Ah;
    __shared__ float sc[256];
    sc[l] = val; __syncthreads();
    for (int off = 1; off < 256; off <<= 1) {
        float t = (l >= off) ? sc[l - off] : 0.f;
        __syncthreads();
        sc[l] += t;
        __syncthreads();
    }
    Acum[(size_t)bid * CH_ + l] = sc[l];
}

// ------------------------------------------------------------------
// pre-transpose: XT[bbx,h][p][t] = conv_x[tt][h*64+p] * dt4[bbx][t]
//                BT[bbx][n][t]   = conv_B[tt][n]
// ------------------------------------------------------------------
__global__ __launch_bounds__(256) void xt_kernel(const bf16* __restrict__ conv,
                                                 const float* __restrict__ dt4,
                                                 bf16* __restrict__ XT,
                                                 bf16* __restrict__ BT) {
    int bid = blockIdx.x;
    int hh = bid % 25;
    int c  = (bid / 25) % NC_;
    int bbx = bid / (25 * NC_);
    int bp = bbx & 1;
    bool flip = bbx >= 2;
    bool isB = (hh == NH_);
    int coff = isB ? DI_ : hh * HD_;
    int tid = threadIdx.x;
    __shared__ short tile[64][72];
    short* dstb = (short*)(isB ? BT : XT);
    size_t rowbase = isB ? (size_t)(bbx * 64) : (size_t)((bbx * NH_ + hh) * 64);
    for (int lt = 0; lt < 4; lt++) {
        __syncthreads();
        #pragma unroll
        for (int it = 0; it < 2; it++) {
            int li = tid + it * 256;
            int r = li >> 3, seg = (li & 7) * 8;
            int t = c * CH_ + lt * 64 + r;
            int tt = flip ? (L_ - 1 - t) : t;
            short8 v = *(const short8*)((const short*)conv + (size_t)(bp * L_ + tt) * CD_ + coff + seg);
            if (!isB) {
                float dtv = dt4[((size_t)(bbx * L_) + t) * NH_ + hh];
                #pragma unroll
                for (int k = 0; k < 8; k++) v[k] = f2s(sb2f(v[k]) * dtv);
            }
            *(short8*)&tile[r][seg] = v;
        }
        __syncthreads();
        #pragma unroll
        for (int it = 0; it < 2; it++) {
            int li = tid + it * 256;
            int p = li >> 3, seg = (li & 7) * 8;
            short8 o;
            #pragma unroll
            for (int k = 0; k < 8; k++) o[k] = tile[seg + k][p];
            *(short8*)(dstb + (rowbase + p) * L_ + c * CH_ + lt * 64 + seg) = o;
        }
    }
}

// ------------------------------------------------------------------
// chunk states (MFMA, direct-load): S^T[p][n] = sum_l XT[p][l]*BT[n][l]*dec[l]
// ------------------------------------------------------------------
__global__ __launch_bounds__(256) void states_kernel(const bf16* __restrict__ XT,
                                                     const bf16* __restrict__ BT,
                                                     const float* __restrict__ Acum,
                                                     bf16* __restrict__ states) {
    int bid = blockIdx.x;
    int h = bid % NH_;
    int c = (bid / NH_) % NC_;
    int bbx = bid / (NH_ * NC_);
    int tid = threadIdx.x;
    int wave = tid >> 6, lane = tid & 63;
    int wr = wave >> 1, wc = wave & 1;
    int fr = lane & 15, kg = (lane >> 4) * 8, rg = (lane >> 4) * 4;
    size_t abase = ((size_t)(bbx * NH_ + h) * NC_ + c) * CH_;
    __shared__ float dec[256];
    {
        float Atot = Acum[abase + CH_ - 1];
        dec[tid] = __expf(Atot - Acum[abase + tid]);
    }
    __syncthreads();
    const short* xbase = (const short*)XT + (size_t)((bbx * NH_ + h) * 64) * L_ + c * CH_;
    const short* bbase = (const short*)BT + (size_t)(bbx * 64) * L_ + c * CH_;
    f32x4 acc[2][2] = {};
    for (int lt = 0; lt < 4; lt++) {
        #pragma unroll
        for (int ks = 0; ks < 2; ks++) {
            int l0 = lt * 64 + ks * 32 + kg;
            float d[8];
            #pragma unroll
            for (int k = 0; k < 8; k++) d[k] = dec[l0 + k];
            short8 af[2], wf[2];
            #pragma unroll
            for (int i = 0; i < 2; i++)
                af[i] = *(const short8*)(xbase + (size_t)(wr*32 + i*16 + fr) * L_ + l0);
            #pragma unroll
            for (int j = 0; j < 2; j++) {
                short8 raw = *(const short8*)(bbase + (size_t)(wc*32 + j*16 + fr) * L_ + l0);
                #pragma unroll
                for (int k = 0; k < 8; k++) raw[k] = f2s(sb2f(raw[k]) * d[k]);
                wf[j] = raw;
            }
            #pragma unroll
            for (int i = 0; i < 2; i++)
                #pragma unroll
                for (int j = 0; j < 2; j++)
                    acc[i][j] = __builtin_amdgcn_mfma_f32_16x16x32_bf16(af[i], wf[j], acc[i][j], 0, 0, 0);
        }
    }
    size_t sbase = (size_t)bid * 4096;
    #pragma unroll
    for (int i = 0; i < 2; i++)
        #pragma unroll
        for (int j = 0; j < 2; j++)
            #pragma unroll
            for (int r = 0; r < 4; r++) {
                int p = wr*32 + i*16 + rg + r;
                int n = wc*32 + j*16 + fr;
                states[sbase + p*64 + n] = f2b(acc[i][j][r]);
            }
}

// ------------------------------------------------------------------
// inter-chunk recurrence, IN-PLACE
// ------------------------------------------------------------------
__global__ __launch_bounds__(256) void chunkscan_kernel(bf16* __restrict__ sp,
                                                        const float* __restrict__ Acum) {
    int bid = blockIdx.x;
    int h = bid % NH_;
    int bbx = bid / NH_;
    int tid = threadIdx.x;
    float run[16];
    #pragma unroll
    for (int k = 0; k < 16; k++) run[k] = 0.f;
    for (int c = 0; c < NC_; c++) {
        float Tc = Acum[((size_t)(bbx * NH_ + h) * NC_ + c) * CH_ + CH_ - 1];
        float ec = __expf(Tc);
        size_t base = ((size_t)(bbx * NC_ + c) * NH_ + h) * 4096;
        #pragma unroll
        for (int k = 0; k < 16; k++) {
            size_t e = tid + k * 256;
            float sv = b2f(sp[base + e]);
            sp[base + e] = f2b(run[k]);
            run[k] = run[k] * ec + sv;
        }
    }
}

// ------------------------------------------------------------------
// Y = Y_diag + Y_off (MFMA, direct-load) — single dispatch, both dirs.
// fwd (bbx<2): yf[b][t] = raw y; bwd: yb[b][t_bwd] = raw y.
// ------------------------------------------------------------------
__global__ __launch_bounds__(256) void ydiag_kernel(const bf16* __restrict__ conv,
                                                    const bf16* __restrict__ XT,
                                                    const float* __restrict__ Acum,
                                                    const bf16* __restrict__ prev,
                                                    bf16* __restrict__ yf,
                                                    bf16* __restrict__ yb) {
    int bid = blockIdx.x;   // ((bbx*NC+c)*NH+h)*4 + lt
    int lt = bid & 3;
    int q  = bid >> 2;
    int h  = q % NH_;
    int r2 = q / NH_;
    int c  = r2 % NC_;
    int bbx = r2 / NC_;
    int bp = bbx & 1;
    bool flip = bbx >= 2;
    int tid = threadIdx.x;
    int wave = tid >> 6, lane = tid & 63;
    int wr = wave >> 1, wc = wave & 1;
    int fr = lane & 15, kg = (lane >> 4) * 8, rg = (lane >> 4) * 4;
    size_t abase = ((size_t)(bbx * NH_ + h) * NC_ + c) * CH_;

    __shared__ short Gt[64 * LDT];
    __shared__ float aL[64], aS[64];
    if (tid < 64) aL[tid] = Acum[abase + lt * 64 + tid];

    short8 cf[2][2];
    #pragma unroll
    for (int i = 0; i < 2; i++) {
        int l = wr*32 + i*16 + fr;
        int t = c * CH_ + lt * 64 + l;
        int tt = flip ? (L_ - 1 - t) : t;
        const short* crow = (const short*)conv + (size_t)(bp * L_ + tt) * CD_ + DI_ + DS_;
        #pragma unroll
        for (int ks = 0; ks < 2; ks++)
            cf[i][ks] = *(const short8*)(crow + ks*32 + kg);
    }

    f32x4 acc[2][2] = {};
    size_t pbase = ((size_t)(bbx * NC_ + c) * NH_ + h) * 4096;
    #pragma unroll
    for (int ks = 0; ks < 2; ks++) {
        #pragma unroll
        for (int j = 0; j < 2; j++) {
            short8 pf = *(const short8*)((const short*)prev + pbase + (size_t)(wc*32 + j*16 + fr)*64 + ks*32 + kg);
            #pragma unroll
            for (int i = 0; i < 2; i++)
                acc[i][j] = __builtin_amdgcn_mfma_f32_16x16x32_bf16(cf[i][ks], pf, acc[i][j], 0, 0, 0);
        }
    }
    __syncthreads();
    #pragma unroll
    for (int i = 0; i < 2; i++)
        #pragma unroll
        for (int r = 0; r < 4; r++) {
            float e = __expf(aL[wr*32 + i*16 + rg + r]);
            #pragma unroll
            for (int j = 0; j < 2; j++) acc[i][j][r] *= e;
        }

    const short* xbase = (const short*)XT + (size_t)((bbx * NH_ + h) * 64) * L_ + c * CH_;

    for (int st = 0; st <= lt; st++) {
        if (tid < 64) aS[tid] = Acum[abase + st * 64 + tid];
        f32x4 gacc[2][2] = {};
        #pragma unroll
        for (int j = 0; j < 2; j++) {
            int s = wc*32 + j*16 + fr;
            int t = c * CH_ + st * 64 + s;
            int tt = flip ? (L_ - 1 - t) : t;
            const short* brow = (const short*)conv + (size_t)(bp * L_ + tt) * CD_ + DI_;
            #pragma unroll
            for (int ks = 0; ks < 2; ks++) {
                short8 bfv = *(const short8*)(brow + ks*32 + kg);
                #pragma unroll
                for (int i = 0; i < 2; i++)
                    gacc[i][j] = __builtin_amdgcn_mfma_f32_16x16x32_bf16(cf[i][ks], bfv, gacc[i][j], 0, 0, 0);
            }
        }
        __syncthreads();
        #pragma unroll
        for (int i = 0; i < 2; i++)
            #pragma unroll
            for (int j = 0; j < 2; j++)
                #pragma unroll
                for (int r = 0; r < 4; r++) {
                    int ll = wr*32 + i*16 + rg + r;
                    int ss = wc*32 + j*16 + fr;
                    bool valid = (st < lt) || (ll >= ss);
                    float gv = valid ? gacc[i][j][r] * __expf(aL[ll] - aS[ss]) : 0.f;
                    Gt[ll * LDT + ss] = f2s(gv);
                }
        __syncthreads();
        #pragma unroll
        for (int ks = 0; ks < 2; ks++) {
            short8 gf[2], xf[2];
            #pragma unroll
            for (int i = 0; i < 2; i++)
                gf[i] = *(const short8*)&Gt[(wr*32 + i*16 + fr)*LDT + ks*32 + kg];
            #pragma unroll
            for (int j = 0; j < 2; j++)
                xf[j] = *(const short8*)(xbase + (size_t)(wc*32 + j*16 + fr)*L_ + st*64 + ks*32 + kg);
            #pragma unroll
            for (int i = 0; i < 2; i++)
                #pragma unroll
                for (int j = 0; j < 2; j++)
                    acc[i][j] = __builtin_amdgcn_mfma_f32_16x16x32_bf16(gf[i], xf[j], acc[i][j], 0, 0, 0);
        }
        __syncthreads();
    }

    bf16* dst = flip ? yb : yf;
    #pragma unroll
    for (int i = 0; i < 2; i++)
        #pragma unroll
        for (int r = 0; r < 4; r++) {
            int l = wr*32 + i*16 + rg + r;
            int t = c * CH_ + lt * 64 + l;
            #pragma unroll
            for (int j = 0; j < 2; j++) {
                int p = wc*32 + j*16 + fr;
                dst[((size_t)(bp * L_) + t) * DI_ + h * HD_ + p] = f2b(acc[i][j][r]);
            }
        }
}

// ------------------------------------------------------------------
// combine: roll/flip-add of yf/yb, D-term GEMV, silu(z) gate, RMSNorm
// ------------------------------------------------------------------
__global__ __launch_bounds__(256) void combine_kernel(const bf16* __restrict__ yf,
                                                      const bf16* __restrict__ yb,
                                                      const bf16* __restrict__ conv,
                                                      const bf16* __restrict__ zbuf,
                                                      const float* __restrict__ fcD,
                                                      const float* __restrict__ Dvec,
                                                      const float* __restrict__ rms_w,
                                                      bf16* __restrict__ ybuf) {
    int row = blockIdx.x;
    int b = row >> 12;
    int t = row & (L_ - 1);
    int tid = threadIdx.x;
    __shared__ float xog_s[DI_];
    __shared__ float dterm_s[NH_];
    __shared__ float rs[4];
    __shared__ float scale_s;
    float yv[6], xog[6], zv[6];
    const bf16* convrow = conv + (size_t)row * CD_;
    const bf16* zrow = zbuf + (size_t)row * DI_;
    const bf16* yfr = (t > 0) ? (yf + (size_t)(row - 1) * DI_) : nullptr;
    const bf16* ybr = (t < L_ - 1) ? (yb + ((size_t)(b * L_) + (L_ - 2 - t)) * DI_) : nullptr;
    #pragma unroll
    for (int k = 0; k < 6; k++) {
        int d = tid + k * 256;
        float xo = b2f(convrow[d]);
        xog[k] = xo; xog_s[d] = xo;
        zv[k] = b2f(zrow[d]);
        float y1 = yfr ? b2f(yfr[d]) : 0.f;
        float y2 = ybr ? b2f(ybr[d]) : 0.f;
        yv[k] = y1 + y2;
    }
    __syncthreads();
    int wid = tid >> 6, lane = tid & 63;
    for (int hh = 0; hh < 6; hh++) {
        int h = wid * 6 + hh;
        float s = 0.f;
        #pragma unroll
        for (int k = 0; k < 24; k++) {
            int d = lane + k * 64;
            s += xog_s[d] * fcD[(size_t)h * DI_ + d];
        }
        for (int off = 32; off > 0; off >>= 1) s += __shfl_down(s, off);
        if (!lane) dterm_s[h] = s + Dvec[h];
    }
    __syncthreads();
    float ss = 0.f;
    #pragma unroll
    for (int k = 0; k < 6; k++) {
        int d = tid + k * 256;
        int h = d >> 6;
        float y = yv[k] + xog[k] * dterm_s[h];
        float z = zv[k];
        y *= z / (1.f + __expf(-z));
        yv[k] = y;
        ss += y * y;
    }
    for (int off = 32; off > 0; off >>= 1) ss += __shfl_down(ss, off);
    if (!lane) rs[wid] = ss;
    __syncthreads();
    if (!tid) scale_s = rsqrtf((rs[0]+rs[1]+rs[2]+rs[3]) / (float)DI_ + EPS_);
    __syncthreads();
    float sc = scale_s;
    bf16* yrow = ybuf + (size_t)row * DI_;
    #pragma unroll
    for (int k = 0; k < 6; k++) {
        int d = tid + k * 256;
        yrow[d] = f2b(yv[k] * sc * rms_w[d]);
    }
}

// ------------------------------------------------------------------
extern "C" void kernel_launch(void* const* d_in, const int* in_sizes, int n_in,
                              void* d_out, int out_size, void* d_ws, size_t ws_size,
                              hipStream_t stream) {
    const float* x        = (const float*)d_in[0];
    const float* ln_w     = (const float*)d_in[1];
    const float* ln_b     = (const float*)d_in[2];
    const float* in_proj  = (const float*)d_in[3];
    const float* conv_w   = (const float*)d_in[4];
    const float* conv_b   = (const float*)d_in[5];
    const float* dt_bias  = (const float*)d_in[6];
    const float* A_log    = (const float*)d_in[7];
    const float* Dvec     = (const float*)d_in[8];
    const float* fc_D_w   = (const float*)d_in[9];
    const float* rms_w    = (const float*)d_in[10];
    const float* out_proj = (const float*)d_in[11];
    float* out = (float*)d_out;

    // ---- workspace layout (lifetime-aliased), ~196 MB ----
    uint8_t* base = (uint8_t*)d_ws;
    size_t off = 0;
    auto alloc = [&](size_t bytes) -> void* {
        void* p = base + off;
        off += (bytes + 255) & ~(size_t)255;
        return p;
    };
    bf16*  buf_z    = (bf16*) alloc((size_t)ROWS_ * DI_ * 2);            // z [2..9]
    uint8_t* regA   = (uint8_t*)alloc((size_t)ROWS_ * CD_ * 2);          // xbc[2..3]/sp[6..8]/y[9..10]
    float* buf_dtr  = (float*)alloc((size_t)ROWS_ * 48 * 4);
    bf16*  buf_conv = (bf16*) alloc((size_t)ROWS_ * CD_ * 2);            // conv [3..9]
    float* buf_dt   = (float*)alloc((size_t)BB4_ * L_ * NH_ * 4);
    float* buf_acum = (float*)alloc((size_t)BB4_ * NH_ * NC_ * CH_ * 4);
    uint8_t* regB   = (uint8_t*)alloc((size_t)ROWS_ * DM_ * 4);          // u[1..2]/yf[8..9]
    bf16*  buf_yb   = (bf16*) alloc((size_t)B_ * L_ * DI_ * 2);          // 25.2 MB [8..9]
    bf16*  w_in_bf  = (bf16*) alloc((size_t)NPAD_ * DM_ * 2);            // padded
    bf16*  w_out_bf = (bf16*) alloc((size_t)DM_ * DI_ * 2);
    bf16*  buf_XT   = (bf16*) alloc((size_t)BB4_ * NH_ * 64 * L_ * 2);   // 50.3 MB
    bf16*  buf_BT   = (bf16*) alloc((size_t)BB4_ * 64 * L_ * 2);         // 2.1 MB

    bf16*  buf_xbc  = (bf16*)regA;
    bf16*  buf_sp   = (bf16*)regA;     // states->prev in place
    bf16*  buf_y    = (bf16*)regA;
    bf16*  buf_u    = (bf16*)regB;
    bf16*  buf_yf   = (bf16*)regB;

    cast_pad_inproj<<<(NPAD_ * DM_ / 4 + 255) / 256, 256, 0, stream>>>(in_proj, w_in_bf);
    cast_f2b<<<(DM_ * DI_ / 4 + 255) / 256, 256, 0, stream>>>(out_proj, w_out_bf, DM_ * DI_);
    ln_kernel<<<ROWS_, 256, 0, stream>>>(x, ln_w, ln_b, buf_u);
    gemm_gl_inproj<<<dim3(NPAD_ / 128, ROWS_ / 128), 256, 0, stream>>>(
        buf_u, w_in_bf, buf_z, buf_xbc, buf_dtr);
    conv_kernel<<<(ROWS_ / 4) * (CD_ / 8) / 256, 256, 0, stream>>>(buf_xbc, conv_w, conv_b, buf_conv);
    dt_kernel<<<(BB4_ * L_ * NH_) / 256, 256, 0, stream>>>(buf_dtr, dt_bias, buf_dt);
    scan_kernel<<<BB4_ * NH_ * NC_, 256, 0, stream>>>(buf_dt, A_log, buf_acum);
    xt_kernel<<<BB4_ * NC_ * 25, 256, 0, stream>>>(buf_conv, buf_dt, buf_XT, buf_BT);
    states_kernel<<<BB4_ * NC_ * NH_, 256, 0, stream>>>(buf_XT, buf_BT, buf_acum, buf_sp);
    chunkscan_kernel<<<BB4_ * NH_, 256, 0, stream>>>(buf_sp, buf_acum);
    ydiag_kernel<<<BB4_ * NC_ * NH_ * 4, 256, 0, stream>>>(buf_conv, buf_XT, buf_acum, buf_sp, buf_yf, buf_yb);
    combine_kernel<<<ROWS_, 256, 0, stream>>>(buf_yf, buf_yb, buf_conv, buf_z, fc_D_w, Dvec, rms_w, buf_y);
    gemm_gl_out<<<dim3(DM_ / 128, ROWS_ / 128), 256, 0, stream>>>(
        buf_y, w_out_bf, x, out);
}

// Round 8
// 524.499 us; speedup vs baseline: 1.0391x; 1.0391x over previous
//
#include <hip/hip_runtime.h>
#include <hip/hip_bf16.h>
#include <cstdint>
#include <cstddef>

typedef __hip_bfloat16 bf16;
typedef __attribute__((ext_vector_type(8))) short short8;
typedef __attribute__((ext_vector_type(4))) float f32x4;

// ---- problem constants ----
#define B_   2
#define L_   4096
#define DM_  768      // d_model
#define DI_  1536     // d_inner
#define NH_  24       // nheads
#define HD_  64       // headdim
#define DS_  64       // d_state
#define CH_  256      // chunk
#define NC_  16       // n chunks
#define CD_  1664     // conv dim
#define DIP_ 3248     // d_in_proj
#define NPAD_ 3328    // in_proj N padded to 26*128
#define EPS_ 1e-5f

#define ROWS_ (B_*L_)        // 8192
#define BB4_  (2*B_)         // 4 ssd batches

#define LDT  72              // Gt LDS row stride (shorts)

__device__ __forceinline__ float b2f(bf16 v) { return __bfloat162float(v); }
__device__ __forceinline__ bf16  f2b(float v) { return __float2bfloat16(v); }
__device__ __forceinline__ float sb2f(short s) {
    bf16 t; __builtin_memcpy(&t, &s, 2); return __bfloat162float(t);
}
__device__ __forceinline__ short f2s(float v) {
    bf16 t = __float2bfloat16(v); short s; __builtin_memcpy(&s, &t, 2); return s;
}
__device__ __forceinline__ void gl_lds16(const void* g, void* l) {
    __builtin_amdgcn_global_load_lds((const __attribute__((address_space(1))) unsigned int*)g,
                                     (__attribute__((address_space(3))) unsigned int*)l,
                                     16, 0, 0);
}

// ------------------------------------------------------------------
// cast f32 -> bf16 (out_proj weights)
// ------------------------------------------------------------------
__global__ __launch_bounds__(256) void cast_f2b(const float* __restrict__ s,
                                                bf16* __restrict__ d, int n) {
    int i = (blockIdx.x * 256 + threadIdx.x) * 4;
    if (i + 3 < n) {
        float4 v = *(const float4*)(s + i);
        d[i]   = f2b(v.x); d[i+1] = f2b(v.y);
        d[i+2] = f2b(v.z); d[i+3] = f2b(v.w);
    } else {
        for (int k = i; k < n; k++) d[k] = f2b(s[k]);
    }
}

// cast + zero-pad rows [3248,3328) for in_proj weights
__global__ __launch_bounds__(256) void cast_pad_inproj(const float* __restrict__ s,
                                                       bf16* __restrict__ d) {
    int i = (blockIdx.x * 256 + threadIdx.x) * 4;
    const int nsrc = DIP_ * DM_;
    const int ntot = NPAD_ * DM_;
    if (i >= ntot) return;
    if (i + 3 < nsrc) {
        float4 v = *(const float4*)(s + i);
        d[i]   = f2b(v.x); d[i+1] = f2b(v.y);
        d[i+2] = f2b(v.z); d[i+3] = f2b(v.w);
    } else {
        for (int k = i; k < i + 4 && k < ntot; k++)
            d[k] = (k < nsrc) ? f2b(s[k]) : f2b(0.f);
    }
}

// ------------------------------------------------------------------
// LayerNorm: one block per row (768), bf16 out
// ------------------------------------------------------------------
__global__ __launch_bounds__(256) void ln_kernel(const float* __restrict__ x,
                                                 const float* __restrict__ w,
                                                 const float* __restrict__ bb,
                                                 bf16* __restrict__ u) {
    int row = blockIdx.x, tid = threadIdx.x;
    const float* xr = x + (size_t)row * DM_;
    float v0 = xr[tid], v1 = xr[tid + 256], v2 = xr[tid + 512];
    float s = v0 + v1 + v2;
    float q = v0*v0 + v1*v1 + v2*v2;
    for (int off = 32; off > 0; off >>= 1) {
        s += __shfl_down(s, off);
        q += __shfl_down(q, off);
    }
    __shared__ float rs[4], rq[4];
    __shared__ float mean_s, rstd_s;
    int lane = tid & 63, wid = tid >> 6;
    if (!lane) { rs[wid] = s; rq[wid] = q; }
    __syncthreads();
    if (!tid) {
        float S = rs[0]+rs[1]+rs[2]+rs[3];
        float Q = rq[0]+rq[1]+rq[2]+rq[3];
        float mu = S / (float)DM_;
        float var = Q / (float)DM_ - mu*mu;
        mean_s = mu; rstd_s = rsqrtf(var + EPS_);
    }
    __syncthreads();
    float mu = mean_s, rstd = rstd_s;
    bf16* ur = u + (size_t)row * DM_;
    ur[tid]       = f2b((v0 - mu) * rstd * w[tid]       + bb[tid]);
    ur[tid + 256] = f2b((v1 - mu) * rstd * w[tid + 256] + bb[tid + 256]);
    ur[tid + 512] = f2b((v2 - mu) * rstd * w[tid + 512] + bb[tid + 512]);
}

// ------------------------------------------------------------------
// m97-style GEMM with global_load_lds + XOR swizzle.
// ------------------------------------------------------------------
__global__ __launch_bounds__(256) void gemm_gl_inproj(const bf16* __restrict__ A,
                                                      const bf16* __restrict__ W,
                                                      bf16* __restrict__ zbuf,
                                                      bf16* __restrict__ xbc,
                                                      float* __restrict__ dtr) {
    __shared__ short As[128 * 32];
    __shared__ short Ws[128 * 32];
    int tid = threadIdx.x;
    int wave = tid >> 6, lane = tid & 63;
    int wm = (wave >> 1) * 64, wn = (wave & 1) * 64;
    int bm = blockIdx.y * 128, bn = blockIdx.x * 128;
    int fr = lane & 15, g = lane >> 4;
    const int K = DM_;
    int srow = lane >> 2;
    int scol = ((lane & 3) ^ ((lane >> 3) & 3)) * 8;
    int rsl = (g ^ ((fr >> 1) & 3)) * 8;
    const short* Ag = (const short*)A;
    const short* Wg = (const short*)W;
    f32x4 acc[4][4] = {};
    for (int k0 = 0; k0 < K; k0 += 32) {
        __syncthreads();
        #pragma unroll
        for (int q = 0; q < 2; q++) {
            gl_lds16(Ag + (size_t)(bm + q*64 + wave*16 + srow) * K + k0 + scol,
                     &As[(q*64 + wave*16) * 32]);
            gl_lds16(Wg + (size_t)(bn + q*64 + wave*16 + srow) * K + k0 + scol,
                     &Ws[(q*64 + wave*16) * 32]);
        }
        __syncthreads();
        short8 af[4], wf[4];
        #pragma unroll
        for (int i = 0; i < 4; i++)
            af[i] = *(const short8*)&As[(wm + i*16 + fr)*32 + rsl];
        #pragma unroll
        for (int j = 0; j < 4; j++)
            wf[j] = *(const short8*)&Ws[(wn + j*16 + fr)*32 + rsl];
        #pragma unroll
        for (int i = 0; i < 4; i++)
            #pragma unroll
            for (int j = 0; j < 4; j++)
                acc[i][j] = __builtin_amdgcn_mfma_f32_16x16x32_bf16(af[i], wf[j], acc[i][j], 0, 0, 0);
    }
    int rg = (lane >> 4) * 4;
    #pragma unroll
    for (int i = 0; i < 4; i++) {
        int mrow = bm + wm + i*16 + rg;
        #pragma unroll
        for (int j = 0; j < 4; j++) {
            int ncol = bn + wn + j*16 + fr;
            #pragma unroll
            for (int r = 0; r < 4; r++) {
                float v = acc[i][j][r];
                int m = mrow + r;
                if (ncol < DI_)            zbuf[(size_t)m * DI_ + ncol] = f2b(v);
                else if (ncol < DI_ + CD_) xbc[(size_t)m * CD_ + (ncol - DI_)] = f2b(v);
                else if (ncol < DIP_)      dtr[(size_t)m * 48 + (ncol - DI_ - CD_)] = v;
            }
        }
    }
}

__global__ __launch_bounds__(256) void gemm_gl_out(const bf16* __restrict__ A,
                                                   const bf16* __restrict__ W,
                                                   const float* __restrict__ resid,
                                                   float* __restrict__ C) {
    __shared__ short As[128 * 32];
    __shared__ short Ws[128 * 32];
    int tid = threadIdx.x;
    int wave = tid >> 6, lane = tid & 63;
    int wm = (wave >> 1) * 64, wn = (wave & 1) * 64;
    int bm = blockIdx.y * 128, bn = blockIdx.x * 128;
    int fr = lane & 15, g = lane >> 4;
    const int K = DI_;
    int srow = lane >> 2;
    int scol = ((lane & 3) ^ ((lane >> 3) & 3)) * 8;
    int rsl = (g ^ ((fr >> 1) & 3)) * 8;
    const short* Ag = (const short*)A;
    const short* Wg = (const short*)W;
    f32x4 acc[4][4] = {};
    for (int k0 = 0; k0 < K; k0 += 32) {
        __syncthreads();
        #pragma unroll
        for (int q = 0; q < 2; q++) {
            gl_lds16(Ag + (size_t)(bm + q*64 + wave*16 + srow) * K + k0 + scol,
                     &As[(q*64 + wave*16) * 32]);
            gl_lds16(Wg + (size_t)(bn + q*64 + wave*16 + srow) * K + k0 + scol,
                     &Ws[(q*64 + wave*16) * 32]);
        }
        __syncthreads();
        short8 af[4], wf[4];
        #pragma unroll
        for (int i = 0; i < 4; i++)
            af[i] = *(const short8*)&As[(wm + i*16 + fr)*32 + rsl];
        #pragma unroll
        for (int j = 0; j < 4; j++)
            wf[j] = *(const short8*)&Ws[(wn + j*16 + fr)*32 + rsl];
        #pragma unroll
        for (int i = 0; i < 4; i++)
            #pragma unroll
            for (int j = 0; j < 4; j++)
                acc[i][j] = __builtin_amdgcn_mfma_f32_16x16x32_bf16(af[i], wf[j], acc[i][j], 0, 0, 0);
    }
    int rg = (lane >> 4) * 4;
    #pragma unroll
    for (int i = 0; i < 4; i++) {
        int mrow = bm + wm + i*16 + rg;
        #pragma unroll
        for (int j = 0; j < 4; j++) {
            int ncol = bn + wn + j*16 + fr;
            #pragma unroll
            for (int r = 0; r < 4; r++) {
                int m = mrow + r;
                C[(size_t)m * DM_ + ncol] = acc[i][j][r] + resid[(size_t)m * DM_ + ncol];
            }
        }
    }
}

// ------------------------------------------------------------------
// Depthwise causal conv7 + SiLU: 8 channels x 8 t per thread.
// window = 14 rows per 8 outputs (1.75x logical reads).
// ------------------------------------------------------------------
__global__ __launch_bounds__(256) void conv_kernel(const bf16* __restrict__ xbc,
                                                   const float* __restrict__ cw,
                                                   const float* __restrict__ cb,
                                                   bf16* __restrict__ out) {
    int bid0 = blockIdx.x;                     // 832 blocks
    int bid = (bid0 & 7) * 104 + (bid0 >> 3);  // XCD t-slab grouping
    int g = bid * 256 + threadIdx.x;           // 212992 threads
    int cg = g % 208;
    int tq = g / 208;                          // b*512 + t0/8
    int b = tq >> 9;
    int t0 = (tq & 511) * 8;
    int c8 = cg * 8;
    const short* src = (const short*)xbc + (size_t)(b * L_) * CD_ + c8;

    float w[7][8], acc[8][8];
    #pragma unroll
    for (int k = 0; k < 8; k++) {
        #pragma unroll
        for (int j = 0; j < 7; j++) w[j][k] = cw[(c8 + k) * 7 + j];
        float bias = cb[c8 + k];
        #pragma unroll
        for (int q = 0; q < 8; q++) acc[q][k] = bias;
    }
    #pragma unroll
    for (int m = 0; m < 14; m++) {
        int tt = t0 - 6 + m;
        float row[8];
        if (tt >= 0) {
            short8 v = *(const short8*)(src + (size_t)tt * CD_);
            #pragma unroll
            for (int k = 0; k < 8; k++) row[k] = sb2f(v[k]);
        } else {
            #pragma unroll
            for (int k = 0; k < 8; k++) row[k] = 0.f;
        }
        #pragma unroll
        for (int q = 0; q < 8; q++) {
            int j = m - q;
            if (j >= 0 && j < 7) {
                #pragma unroll
                for (int k = 0; k < 8; k++) acc[q][k] += row[k] * w[j][k];
            }
        }
    }
    #pragma unroll
    for (int q = 0; q < 8; q++) {
        short8 o;
        #pragma unroll
        for (int k = 0; k < 8; k++) {
            float a = acc[q][k];
            a = a / (1.f + __expf(-a));
            o[k] = f2s(a);
        }
        *(short8*)((short*)out + (size_t)(b * L_ + t0 + q) * CD_ + c8) = o;
    }
}

// ------------------------------------------------------------------
// dt: softplus(dt2 + bias) with flip for bwd batches
// ------------------------------------------------------------------
__global__ __launch_bounds__(256) void dt_kernel(const float* __restrict__ dtr,
                                                 const float* __restrict__ dt_bias,
                                                 float* __restrict__ dt4) {
    int idx = blockIdx.x * 256 + threadIdx.x;
    if (idx >= BB4_ * L_ * NH_) return;
    int h = idx % NH_;
    int t = (idx / NH_) % L_;
    int bbx = idx / (NH_ * L_);
    int bp = bbx & 1;
    float raw;
    if (bbx < 2) raw = dtr[((size_t)(bp * L_ + t)) * 48 + h];
    else         raw = dtr[((size_t)(bp * L_ + (L_ - 1 - t))) * 48 + NH_ + h];
    float v = raw + dt_bias[h];
    float dt = (v > 20.f) ? v : log1pf(__expf(v));
    dt4[idx] = dt;
}

// ------------------------------------------------------------------
// per-chunk inclusive cumsum of dt*A
// ------------------------------------------------------------------
__global__ __launch_bounds__(256) void scan_kernel(const float* __restrict__ dt4,
                                                   const float* __restrict__ A_log,
                                                   float* __restrict__ Acum) {
    int bid = blockIdx.x;
    int c  = bid % NC_;
    int h  = (bid / NC_) % NH_;
    int bbx = bid / (NC_ * NH_);
    int l = threadIdx.x;
    float Ah = -__expf(A_log[h]);
    float val = dt4[((size_t)(bbx * L_) + c * CH_ + l) * NH_ + h] * Ah;
    __shared__ float sc[256];
    sc[l] = val; __syncthreads();
    for (int off = 1; off < 256; off <<= 1) {
        float t = (l >= off) ? sc[l - off] : 0.f;
        __syncthreads();
        sc[l] += t;
        __syncthreads();
    }
    Acum[(size_t)bid * CH_ + l] = sc[l];
}

// ------------------------------------------------------------------
// pre-transpose: XT[bbx,h][p][t] = conv_x[tt][h*64+p] * dt4[bbx][t]
//                BT[bbx][n][t]   = conv_B[tt][n]
// ------------------------------------------------------------------
__global__ __launch_bounds__(256) void xt_kernel(const bf16* __restrict__ conv,
                                                 const float* __restrict__ dt4,
                                                 bf16* __restrict__ XT,
                                                 bf16* __restrict__ BT) {
    int bid0 = blockIdx.x;                       // 1600
    int bid = (bid0 & 7) * 200 + (bid0 >> 3);    // XCD (bbx,c) grouping
    int hh = bid % 25;
    int c  = (bid / 25) % NC_;
    int bbx = bid / (25 * NC_);
    int bp = bbx & 1;
    bool flip = bbx >= 2;
    bool isB = (hh == NH_);
    int coff = isB ? DI_ : hh * HD_;
    int tid = threadIdx.x;
    __shared__ short tile[64][72];
    short* dstb = (short*)(isB ? BT : XT);
    size_t rowbase = isB ? (size_t)(bbx * 64) : (size_t)((bbx * NH_ + hh) * 64);
    for (int lt = 0; lt < 4; lt++) {
        __syncthreads();
        #pragma unroll
        for (int it = 0; it < 2; it++) {
            int li = tid + it * 256;
            int r = li >> 3, seg = (li & 7) * 8;
            int t = c * CH_ + lt * 64 + r;
            int tt = flip ? (L_ - 1 - t) : t;
            short8 v = *(const short8*)((const short*)conv + (size_t)(bp * L_ + tt) * CD_ + coff + seg);
            if (!isB) {
                float dtv = dt4[((size_t)(bbx * L_) + t) * NH_ + hh];
                #pragma unroll
                for (int k = 0; k < 8; k++) v[k] = f2s(sb2f(v[k]) * dtv);
            }
            *(short8*)&tile[r][seg] = v;
        }
        __syncthreads();
        #pragma unroll
        for (int it = 0; it < 2; it++) {
            int li = tid + it * 256;
            int p = li >> 3, seg = (li & 7) * 8;
            short8 o;
            #pragma unroll
            for (int k = 0; k < 8; k++) o[k] = tile[seg + k][p];
            *(short8*)(dstb + (rowbase + p) * L_ + c * CH_ + lt * 64 + seg) = o;
        }
    }
}

// ------------------------------------------------------------------
// chunk states (MFMA, direct-load): S^T[p][n] = sum_l XT[p][l]*BT[n][l]*dec[l]
// ------------------------------------------------------------------
__global__ __launch_bounds__(256) void states_kernel(const bf16* __restrict__ XT,
                                                     const bf16* __restrict__ BT,
                                                     const float* __restrict__ Acum,
                                                     bf16* __restrict__ states) {
    int bid0 = blockIdx.x;                       // 1536
    int bid = (bid0 & 7) * 192 + (bid0 >> 3);    // XCD (bbx,c) grouping
    int h = bid % NH_;
    int c = (bid / NH_) % NC_;
    int bbx = bid / (NH_ * NC_);
    int tid = threadIdx.x;
    int wave = tid >> 6, lane = tid & 63;
    int wr = wave >> 1, wc = wave & 1;
    int fr = lane & 15, kg = (lane >> 4) * 8, rg = (lane >> 4) * 4;
    size_t abase = ((size_t)(bbx * NH_ + h) * NC_ + c) * CH_;
    __shared__ float dec[256];
    {
        float Atot = Acum[abase + CH_ - 1];
        dec[tid] = __expf(Atot - Acum[abase + tid]);
    }
    __syncthreads();
    const short* xbase = (const short*)XT + (size_t)((bbx * NH_ + h) * 64) * L_ + c * CH_;
    const short* bbase = (const short*)BT + (size_t)(bbx * 64) * L_ + c * CH_;
    f32x4 acc[2][2] = {};
    for (int lt = 0; lt < 4; lt++) {
        #pragma unroll
        for (int ks = 0; ks < 2; ks++) {
            int l0 = lt * 64 + ks * 32 + kg;
            float d[8];
            #pragma unroll
            for (int k = 0; k < 8; k++) d[k] = dec[l0 + k];
            short8 af[2], wf[2];
            #pragma unroll
            for (int i = 0; i < 2; i++)
                af[i] = *(const short8*)(xbase + (size_t)(wr*32 + i*16 + fr) * L_ + l0);
            #pragma unroll
            for (int j = 0; j < 2; j++) {
                short8 raw = *(const short8*)(bbase + (size_t)(wc*32 + j*16 + fr) * L_ + l0);
                #pragma unroll
                for (int k = 0; k < 8; k++) raw[k] = f2s(sb2f(raw[k]) * d[k]);
                wf[j] = raw;
            }
            #pragma unroll
            for (int i = 0; i < 2; i++)
                #pragma unroll
                for (int j = 0; j < 2; j++)
                    acc[i][j] = __builtin_amdgcn_mfma_f32_16x16x32_bf16(af[i], wf[j], acc[i][j], 0, 0, 0);
        }
    }
    size_t sbase = (size_t)bid * 4096;
    #pragma unroll
    for (int i = 0; i < 2; i++)
        #pragma unroll
        for (int j = 0; j < 2; j++)
            #pragma unroll
            for (int r = 0; r < 4; r++) {
                int p = wr*32 + i*16 + rg + r;
                int n = wc*32 + j*16 + fr;
                states[sbase + p*64 + n] = f2b(acc[i][j][r]);
            }
}

// ------------------------------------------------------------------
// inter-chunk recurrence, IN-PLACE
// ------------------------------------------------------------------
__global__ __launch_bounds__(256) void chunkscan_kernel(bf16* __restrict__ sp,
                                                        const float* __restrict__ Acum) {
    int bid = blockIdx.x;
    int h = bid % NH_;
    int bbx = bid / NH_;
    int tid = threadIdx.x;
    float run[16];
    #pragma unroll
    for (int k = 0; k < 16; k++) run[k] = 0.f;
    for (int c = 0; c < NC_; c++) {
        float Tc = Acum[((size_t)(bbx * NH_ + h) * NC_ + c) * CH_ + CH_ - 1];
        float ec = __expf(Tc);
        size_t base = ((size_t)(bbx * NC_ + c) * NH_ + h) * 4096;
        #pragma unroll
        for (int k = 0; k < 16; k++) {
            size_t e = tid + k * 256;
            float sv = b2f(sp[base + e]);
            sp[base + e] = f2b(run[k]);
            run[k] = run[k] * ec + sv;
        }
    }
}

// ------------------------------------------------------------------
// Y = Y_diag + Y_off (MFMA, reg-prefetch pipeline + XCD swizzle)
// ------------------------------------------------------------------
__global__ __launch_bounds__(256) void ydiag_kernel(const bf16* __restrict__ conv,
                                                    const bf16* __restrict__ XT,
                                                    const float* __restrict__ Acum,
                                                    const bf16* __restrict__ prev,
                                                    bf16* __restrict__ yf,
                                                    bf16* __restrict__ yb) {
    int bid0 = blockIdx.x;                       // 6144
    int bid = (bid0 & 7) * 768 + (bid0 >> 3);    // XCD (bbx,c) grouping
    int lt = bid & 3;
    int q  = bid >> 2;
    int h  = q % NH_;
    int r2 = q / NH_;
    int c  = r2 % NC_;
    int bbx = r2 / NC_;
    int bp = bbx & 1;
    bool flip = bbx >= 2;
    int tid = threadIdx.x;
    int wave = tid >> 6, lane = tid & 63;
    int wr = wave >> 1, wc = wave & 1;
    int fr = lane & 15, kg = (lane >> 4) * 8, rg = (lane >> 4) * 4;
    size_t abase = ((size_t)(bbx * NH_ + h) * NC_ + c) * CH_;

    __shared__ short Gt[64 * LDT];

    // decay row-values in registers (no LDS, no barrier)
    float aLv[2][4];
    #pragma unroll
    for (int i = 0; i < 2; i++)
        #pragma unroll
        for (int r = 0; r < 4; r++)
            aLv[i][r] = Acum[abase + lt * 64 + wr*32 + i*16 + rg + r];

    // C fragments in registers for whole kernel
    short8 cf[2][2];
    #pragma unroll
    for (int i = 0; i < 2; i++) {
        int l = wr*32 + i*16 + fr;
        int t = c * CH_ + lt * 64 + l;
        int tt = flip ? (L_ - 1 - t) : t;
        const short* crow = (const short*)conv + (size_t)(bp * L_ + tt) * CD_ + DI_ + DS_;
        #pragma unroll
        for (int ks = 0; ks < 2; ks++)
            cf[i][ks] = *(const short8*)(crow + ks*32 + kg);
    }

    // Y_off = (C @ prevT) * exp(aL)
    f32x4 acc[2][2] = {};
    size_t pbase = ((size_t)(bbx * NC_ + c) * NH_ + h) * 4096;
    #pragma unroll
    for (int ks = 0; ks < 2; ks++) {
        #pragma unroll
        for (int j = 0; j < 2; j++) {
            short8 pf = *(const short8*)((const short*)prev + pbase + (size_t)(wc*32 + j*16 + fr)*64 + ks*32 + kg);
            #pragma unroll
            for (int i = 0; i < 2; i++)
                acc[i][j] = __builtin_amdgcn_mfma_f32_16x16x32_bf16(cf[i][ks], pf, acc[i][j], 0, 0, 0);
        }
    }
    #pragma unroll
    for (int i = 0; i < 2; i++)
        #pragma unroll
        for (int r = 0; r < 4; r++) {
            float e = __expf(aLv[i][r]);
            #pragma unroll
            for (int j = 0; j < 2; j++) acc[i][j][r] *= e;
        }

    const short* xbase = (const short*)XT + (size_t)((bbx * NH_ + h) * 64) * L_ + c * CH_;

    // --- st loop with register double-buffered B / aS ---
    short8 bf_c[2][2];
    float aSc[2];
    #pragma unroll
    for (int j = 0; j < 2; j++) {
        int s = wc*32 + j*16 + fr;
        int t = c * CH_ + s;
        int tt = flip ? (L_ - 1 - t) : t;
        const short* brow = (const short*)conv + (size_t)(bp * L_ + tt) * CD_ + DI_;
        #pragma unroll
        for (int ks = 0; ks < 2; ks++)
            bf_c[j][ks] = *(const short8*)(brow + ks*32 + kg);
        aSc[j] = Acum[abase + s];
    }

    for (int st = 0; st <= lt; st++) {
        // X fragments for current st (latency hidden under G phase)
        short8 xf[2][2];
        #pragma unroll
        for (int j = 0; j < 2; j++)
            #pragma unroll
            for (int ks = 0; ks < 2; ks++)
                xf[j][ks] = *(const short8*)(xbase + (size_t)(wc*32 + j*16 + fr)*L_ + st*64 + ks*32 + kg);
        // prefetch next-st B / aS
        short8 bf_n[2][2];
        float aSn[2];
        if (st < lt) {
            #pragma unroll
            for (int j = 0; j < 2; j++) {
                int s = wc*32 + j*16 + fr;
                int t = c * CH_ + (st+1) * 64 + s;
                int tt = flip ? (L_ - 1 - t) : t;
                const short* brow = (const short*)conv + (size_t)(bp * L_ + tt) * CD_ + DI_;
                #pragma unroll
                for (int ks = 0; ks < 2; ks++)
                    bf_n[j][ks] = *(const short8*)(brow + ks*32 + kg);
                aSn[j] = Acum[abase + (st+1)*64 + s];
            }
        }
        // G = C @ B^T
        f32x4 gacc[2][2] = {};
        #pragma unroll
        for (int ks = 0; ks < 2; ks++)
            #pragma unroll
            for (int j = 0; j < 2; j++)
                #pragma unroll
                for (int i = 0; i < 2; i++)
                    gacc[i][j] = __builtin_amdgcn_mfma_f32_16x16x32_bf16(cf[i][ks], bf_c[j][ks], gacc[i][j], 0, 0, 0);
        // mask + decay -> Gt
        #pragma unroll
        for (int i = 0; i < 2; i++)
            #pragma unroll
            for (int j = 0; j < 2; j++)
                #pragma unroll
                for (int r = 0; r < 4; r++) {
                    int ll = wr*32 + i*16 + rg + r;
                    int ss = wc*32 + j*16 + fr;
                    bool valid = (st < lt) || (ll >= ss);
                    float gv = valid ? gacc[i][j][r] * __expf(aLv[i][r] - aSc[j]) : 0.f;
                    Gt[ll * LDT + ss] = f2s(gv);
                }
        __syncthreads();
        // Y += G~ @ X
        #pragma unroll
        for (int ks = 0; ks < 2; ks++) {
            short8 gf[2];
            #pragma unroll
            for (int i = 0; i < 2; i++)
                gf[i] = *(const short8*)&Gt[(wr*32 + i*16 + fr)*LDT + ks*32 + kg];
            #pragma unroll
            for (int i = 0; i < 2; i++)
                #pragma unroll
                for (int j = 0; j < 2; j++)
                    acc[i][j] = __builtin_amdgcn_mfma_f32_16x16x32_bf16(gf[i], xf[j][ks], acc[i][j], 0, 0, 0);
        }
        __syncthreads();
        if (st < lt) {
            #pragma unroll
            for (int j = 0; j < 2; j++) {
                #pragma unroll
                for (int ks = 0; ks < 2; ks++) bf_c[j][ks] = bf_n[j][ks];
                aSc[j] = aSn[j];
            }
        }
    }

    bf16* dst = flip ? yb : yf;
    #pragma unroll
    for (int i = 0; i < 2; i++)
        #pragma unroll
        for (int r = 0; r < 4; r++) {
            int l = wr*32 + i*16 + rg + r;
            int t = c * CH_ + lt * 64 + l;
            #pragma unroll
            for (int j = 0; j < 2; j++) {
                int p = wc*32 + j*16 + fr;
                dst[((size_t)(bp * L_) + t) * DI_ + h * HD_ + p] = f2b(acc[i][j][r]);
            }
        }
}

// ------------------------------------------------------------------
// combine: roll/flip-add of yf/yb, D-term GEMV, silu(z) gate, RMSNorm
// ------------------------------------------------------------------
__global__ __launch_bounds__(256) void combine_kernel(const bf16* __restrict__ yf,
                                                      const bf16* __restrict__ yb,
                                                      const bf16* __restrict__ conv,
                                                      const bf16* __restrict__ zbuf,
                                                      const float* __restrict__ fcD,
                                                      const float* __restrict__ Dvec,
                                                      const float* __restrict__ rms_w,
                                                      bf16* __restrict__ ybuf) {
    int row = blockIdx.x;
    int b = row >> 12;
    int t = row & (L_ - 1);
    int tid = threadIdx.x;
    __shared__ float xog_s[DI_];
    __shared__ float dterm_s[NH_];
    __shared__ float rs[4];
    __shared__ float scale_s;
    float yv[6], xog[6], zv[6];
    const bf16* convrow = conv + (size_t)row * CD_;
    const bf16* zrow = zbuf + (size_t)row * DI_;
    const bf16* yfr = (t > 0) ? (yf + (size_t)(row - 1) * DI_) : nullptr;
    const bf16* ybr = (t < L_ - 1) ? (yb + ((size_t)(b * L_) + (L_ - 2 - t)) * DI_) : nullptr;
    #pragma unroll
    for (int k = 0; k < 6; k++) {
        int d = tid + k * 256;
        float xo = b2f(convrow[d]);
        xog[k] = xo; xog_s[d] = xo;
        zv[k] = b2f(zrow[d]);
        float y1 = yfr ? b2f(yfr[d]) : 0.f;
        float y2 = ybr ? b2f(ybr[d]) : 0.f;
        yv[k] = y1 + y2;
    }
    __syncthreads();
    int wid = tid >> 6, lane = tid & 63;
    for (int hh = 0; hh < 6; hh++) {
        int h = wid * 6 + hh;
        float s = 0.f;
        #pragma unroll
        for (int k = 0; k < 24; k++) {
            int d = lane + k * 64;
            s += xog_s[d] * fcD[(size_t)h * DI_ + d];
        }
        for (int off = 32; off > 0; off >>= 1) s += __shfl_down(s, off);
        if (!lane) dterm_s[h] = s + Dvec[h];
    }
    __syncthreads();
    float ss = 0.f;
    #pragma unroll
    for (int k = 0; k < 6; k++) {
        int d = tid + k * 256;
        int h = d >> 6;
        float y = yv[k] + xog[k] * dterm_s[h];
        float z = zv[k];
        y *= z / (1.f + __expf(-z));
        yv[k] = y;
        ss += y * y;
    }
    for (int off = 32; off > 0; off >>= 1) ss += __shfl_down(ss, off);
    if (!lane) rs[wid] = ss;
    __syncthreads();
    if (!tid) scale_s = rsqrtf((rs[0]+rs[1]+rs[2]+rs[3]) / (float)DI_ + EPS_);
    __syncthreads();
    float sc = scale_s;
    bf16* yrow = ybuf + (size_t)row * DI_;
    #pragma unroll
    for (int k = 0; k < 6; k++) {
        int d = tid + k * 256;
        yrow[d] = f2b(yv[k] * sc * rms_w[d]);
    }
}

// ------------------------------------------------------------------
extern "C" void kernel_launch(void* const* d_in, const int* in_sizes, int n_in,
                              void* d_out, int out_size, void* d_ws, size_t ws_size,
                              hipStream_t stream) {
    const float* x        = (const float*)d_in[0];
    const float* ln_w     = (const float*)d_in[1];
    const float* ln_b     = (const float*)d_in[2];
    const float* in_proj  = (const float*)d_in[3];
    const float* conv_w   = (const float*)d_in[4];
    const float* conv_b   = (const float*)d_in[5];
    const float* dt_bias  = (const float*)d_in[6];
    const float* A_log    = (const float*)d_in[7];
    const float* Dvec     = (const float*)d_in[8];
    const float* fc_D_w   = (const float*)d_in[9];
    const float* rms_w    = (const float*)d_in[10];
    const float* out_proj = (const float*)d_in[11];
    float* out = (float*)d_out;

    // ---- workspace layout (lifetime-aliased), ~196 MB ----
    uint8_t* base = (uint8_t*)d_ws;
    size_t off = 0;
    auto alloc = [&](size_t bytes) -> void* {
        void* p = base + off;
        off += (bytes + 255) & ~(size_t)255;
        return p;
    };
    bf16*  buf_z    = (bf16*) alloc((size_t)ROWS_ * DI_ * 2);
    uint8_t* regA   = (uint8_t*)alloc((size_t)ROWS_ * CD_ * 2);
    float* buf_dtr  = (float*)alloc((size_t)ROWS_ * 48 * 4);
    bf16*  buf_conv = (bf16*) alloc((size_t)ROWS_ * CD_ * 2);
    float* buf_dt   = (float*)alloc((size_t)BB4_ * L_ * NH_ * 4);
    float* buf_acum = (float*)alloc((size_t)BB4_ * NH_ * NC_ * CH_ * 4);
    uint8_t* regB   = (uint8_t*)alloc((size_t)ROWS_ * DM_ * 4);
    bf16*  buf_yb   = (bf16*) alloc((size_t)B_ * L_ * DI_ * 2);
    bf16*  w_in_bf  = (bf16*) alloc((size_t)NPAD_ * DM_ * 2);
    bf16*  w_out_bf = (bf16*) alloc((size_t)DM_ * DI_ * 2);
    bf16*  buf_XT   = (bf16*) alloc((size_t)BB4_ * NH_ * 64 * L_ * 2);
    bf16*  buf_BT   = (bf16*) alloc((size_t)BB4_ * 64 * L_ * 2);

    bf16*  buf_xbc  = (bf16*)regA;
    bf16*  buf_sp   = (bf16*)regA;
    bf16*  buf_y    = (bf16*)regA;
    bf16*  buf_u    = (bf16*)regB;
    bf16*  buf_yf   = (bf16*)regB;

    cast_pad_inproj<<<(NPAD_ * DM_ / 4 + 255) / 256, 256, 0, stream>>>(in_proj, w_in_bf);
    cast_f2b<<<(DM_ * DI_ / 4 + 255) / 256, 256, 0, stream>>>(out_proj, w_out_bf, DM_ * DI_);
    ln_kernel<<<ROWS_, 256, 0, stream>>>(x, ln_w, ln_b, buf_u);
    gemm_gl_inproj<<<dim3(NPAD_ / 128, ROWS_ / 128), 256, 0, stream>>>(
        buf_u, w_in_bf, buf_z, buf_xbc, buf_dtr);
    conv_kernel<<<832, 256, 0, stream>>>(buf_xbc, conv_w, conv_b, buf_conv);
    dt_kernel<<<(BB4_ * L_ * NH_) / 256, 256, 0, stream>>>(buf_dtr, dt_bias, buf_dt);
    scan_kernel<<<BB4_ * NH_ * NC_, 256, 0, stream>>>(buf_dt, A_log, buf_acum);
    xt_kernel<<<BB4_ * NC_ * 25, 256, 0, stream>>>(buf_conv, buf_dt, buf_XT, buf_BT);
    states_kernel<<<BB4_ * NC_ * NH_, 256, 0, stream>>>(buf_XT, buf_BT, buf_acum, buf_sp);
    chunkscan_kernel<<<BB4_ * NH_, 256, 0, stream>>>(buf_sp, buf_acum);
    ydiag_kernel<<<BB4_ * NC_ * NH_ * 4, 256, 0, stream>>>(buf_conv, buf_XT, buf_acum, buf_sp, buf_yf, buf_yb);
    combine_kernel<<<ROWS_, 256, 0, stream>>>(buf_yf, buf_yb, buf_conv, buf_z, fc_D_w, Dvec, rms_w, buf_y);
    gemm_gl_out<<<dim3(DM_ / 128, ROWS_ / 128), 256, 0, stream>>>(
        buf_y, w_out_bf, x, out);
}